// Round 4
// baseline (1831.212 us; speedup 1.0000x reference)
//
#include <hip/hip_runtime.h>
#include <hip/hip_bf16.h>
#include <stdint.h>

#define HIDDEN 4096
#define INTER  14336
#define NSEL   4096

using short8 = __attribute__((ext_vector_type(8))) short;
using f32x16 = __attribute__((ext_vector_type(16))) float;

__device__ __forceinline__ uint16_t f2bf(float f) {
  uint32_t u = __float_as_uint(f);
  uint32_t r = (u + 0x7FFFu + ((u >> 16) & 1u)) >> 16;
  return (uint16_t)r;
}
__device__ __forceinline__ float bf2f(uint16_t h) {
  return __uint_as_float(((uint32_t)h) << 16);
}
__device__ __forceinline__ uint32_t pack2(float lo, float hi) {
  return (uint32_t)f2bf(lo) | ((uint32_t)f2bf(hi) << 16);
}

// ---- fp32 -> bf16 conversion, 8 elems/thread ----
__global__ void cvt_f32_bf16(const float* __restrict__ in, uint16_t* __restrict__ out) {
  size_t i = ((size_t)blockIdx.x * 256 + threadIdx.x) * 8;
  float4 a = *(const float4*)(in + i);
  float4 b = *(const float4*)(in + i + 4);
  uint4 v;
  v.x = pack2(a.x, a.y); v.y = pack2(a.z, a.w);
  v.z = pack2(b.x, b.y); v.w = pack2(b.z, b.w);
  *(uint4*)(out + i) = v;
}

// ---- gather selected tokens + cast to bf16 ----
__global__ void gather_cast(const float* __restrict__ x, const int* __restrict__ idx,
                            uint16_t* __restrict__ xs) {
  const int n = blockIdx.x;
  const int t = threadIdx.x;
  const size_t s = (size_t)idx[n] * HIDDEN + (size_t)t * 16;
  const size_t d = (size_t)n * HIDDEN + (size_t)t * 16;
  const float4* sp = (const float4*)(x + s);
  float4 f0 = sp[0], f1 = sp[1], f2 = sp[2], f3 = sp[3];
  uint4 v0, v1;
  v0.x = pack2(f0.x, f0.y); v0.y = pack2(f0.z, f0.w);
  v0.z = pack2(f1.x, f1.y); v0.w = pack2(f1.z, f1.w);
  v1.x = pack2(f2.x, f2.y); v1.y = pack2(f2.z, f2.w);
  v1.z = pack2(f3.x, f3.y); v1.w = pack2(f3.z, f3.w);
  *(uint4*)(xs + d)     = v0;
  *(uint4*)(xs + d + 8) = v1;
}

__device__ __forceinline__ void gload16(const void* g, void* l) {
  __builtin_amdgcn_global_load_lds(
      (const __attribute__((address_space(1))) void*)g,
      (__attribute__((address_space(3))) void*)l, 16, 0, 0);
}

// ============================================================================
// NT GEMM: C[M][N] = A[M][K]*B[N][K]^T, bf16 in, fp32 acc.
// 256(M) x 128(N) block tile, BK=32, 8 waves (4M x 2N) of 64x64, 512 thr.
// mfma_f32_32x32x16_bf16 (2495 TF pipe vs 2075 for 16x16).
// Ring-3 LDS (3 x (A 16KB + B 8KB) = 72 KiB) -> 2 blocks/CU, 16 waves/CU:
// cross-block TLP overlaps one block's LDS phase with the other's MFMAs.
// Stage t+2 during tile t; end-of-tile s_waitcnt vmcnt(3) certifies t+1
// (t+2's 3 loads stay in flight; never drains mid-loop). One s_barrier/tile.
// T2 swizzle: line = 2 rows x 32 cols = 128B; 16B-slot ^= (line&7), applied
// via pre-inverse-swizzled global source (gload_lds dest linear, rule 21)
// + swizzled read offsets. Per-16-lane-group aliasing is 2-way (free).
// A/B frag (32x32x16): lane reads 16B at row (lane&31), k-off (lane>>5)*8.
// C/D layout: col = lane&31, row = (reg&3) + 8*(reg>>2) + 4*(lane>>5).
// EPI 0: store bf16 g. EPI 1: h = silu(g)*acc overwrite. EPI 2: out=acc*wt.
// ============================================================================
template<int EPI>
__global__ __launch_bounds__(512, 4) void gemm_nt(
    const uint16_t* __restrict__ A,
    const uint16_t* __restrict__ B,
    uint16_t* __restrict__ G,
    float* __restrict__ O,
    const float* __restrict__ Wt,
    int N, int K, int nbm)
{
  __shared__ __align__(16) uint16_t lds[3][12288];   // slot: A[0..8191] B[8192..12287]

  const int nwg = (int)gridDim.x;
  const int lid = ((int)blockIdx.x & 7) * (nwg >> 3) + ((int)blockIdx.x >> 3);
  const int bm = lid % nbm, bn = lid / nbm;

  const int tid  = (int)threadIdx.x;
  const int lane = tid & 63, w = tid >> 6;
  const int wm = w >> 1, wn = w & 1;       // wave tile: rows wm*64, cols wn*64
  const int l31 = lane & 31, kh = lane >> 5;

  // fragment read offsets (u16, slot-relative), swizzled
  int offA[2][2], offB[2][2];
#pragma unroll
  for (int m = 0; m < 2; ++m)
#pragma unroll
    for (int kk = 0; kk < 2; ++kk) {
      const int r = wm * 64 + m * 32 + l31;
      const int q = r >> 1;
      const int sl = (r & 1) * 4 + kk * 2 + kh;
      offA[m][kk] = q * 64 + ((sl ^ (q & 7)) * 8);
    }
#pragma unroll
  for (int n = 0; n < 2; ++n)
#pragma unroll
    for (int kk = 0; kk < 2; ++kk) {
      const int r = wn * 64 + n * 32 + l31;
      const int q = r >> 1;
      const int sl = (r & 1) * 4 + kk * 2 + kh;
      offB[n][kk] = 8192 + q * 64 + ((sl ^ (q & 7)) * 8);
    }

  // staging: inverse-swizzled global source, linear gload_lds dest
  const int su   = (tid & 7) ^ ((tid >> 3) & 7);
  const int sRow = 2 * (tid >> 3) + (su >> 2);
  const int sCol = (su & 3) * 8;
  const uint16_t* aSrc = A + (size_t)(bm * 256 + sRow) * K + sCol;
  const uint16_t* bSrc = B + (size_t)(bn * 128 + sRow) * K + sCol;
  const size_t rowStepA = (size_t)128 * K;

#define STAGE(tt, s) do { \
    const uint16_t* _pa = aSrc + (size_t)(tt) * 32; \
    gload16(_pa,            &lds[s][tid * 8]); \
    gload16(_pa + rowStepA, &lds[s][4096 + tid * 8]); \
    gload16(bSrc + (size_t)(tt) * 32, &lds[s][8192 + tid * 8]); \
  } while (0)

  f32x16 acc[2][2];
#pragma unroll
  for (int m = 0; m < 2; ++m)
#pragma unroll
    for (int n = 0; n < 2; ++n)
#pragma unroll
      for (int j = 0; j < 16; ++j) acc[m][n][j] = 0.f;

  const int nk = K >> 5;

  // prologue: stage tiles 0,1; certify tile 0 (tile 1's 3 loads in flight)
  STAGE(0, 0);
  STAGE(1, 1);
  asm volatile("s_waitcnt vmcnt(3)" ::: "memory");
  __builtin_amdgcn_s_barrier();

  for (int t = 0; t < nk; ++t) {
    const uint16_t* S = &lds[t % 3][0];

    if (t + 2 < nk) STAGE(t + 2, (t + 2) % 3);

#pragma unroll
    for (int kk = 0; kk < 2; ++kk) {
      short8 a0 = *(const short8*)&S[offA[0][kk]];
      short8 a1 = *(const short8*)&S[offA[1][kk]];
      short8 b0 = *(const short8*)&S[offB[0][kk]];
      short8 b1 = *(const short8*)&S[offB[1][kk]];
      __builtin_amdgcn_s_setprio(1);
      acc[0][0] = __builtin_amdgcn_mfma_f32_32x32x16_bf16(a0, b0, acc[0][0], 0, 0, 0);
      acc[0][1] = __builtin_amdgcn_mfma_f32_32x32x16_bf16(a0, b1, acc[0][1], 0, 0, 0);
      acc[1][0] = __builtin_amdgcn_mfma_f32_32x32x16_bf16(a1, b0, acc[1][0], 0, 0, 0);
      acc[1][1] = __builtin_amdgcn_mfma_f32_32x32x16_bf16(a1, b1, acc[1][1], 0, 0, 0);
      __builtin_amdgcn_s_setprio(0);
    }

    // certify tile t+1; keep t+2's loads in flight
    if      (t + 2 < nk) { asm volatile("s_waitcnt vmcnt(3)" ::: "memory"); }
    else if (t + 1 < nk) { asm volatile("s_waitcnt vmcnt(0)" ::: "memory"); }
    __builtin_amdgcn_s_barrier();
  }
#undef STAGE

  // epilogue (32x32 C/D): col=lane&31, row=(reg&3)+8*(reg>>2)+4*(lane>>5)
  const int row0 = bm * 256 + wm * 64, col0 = bn * 128 + wn * 64;
#pragma unroll
  for (int m = 0; m < 2; ++m)
#pragma unroll
    for (int n = 0; n < 2; ++n) {
      const int c = col0 + n * 32 + l31;
#pragma unroll
      for (int reg = 0; reg < 16; ++reg) {
        const int r = row0 + m * 32 + (reg & 3) + 8 * (reg >> 2) + 4 * kh;
        const float v = acc[m][n][reg];
        if constexpr (EPI == 0) {
          __builtin_nontemporal_store(f2bf(v), &G[(size_t)r * N + c]);
        } else if constexpr (EPI == 1) {
          float gf = bf2f(G[(size_t)r * N + c]);
          float h = gf / (1.f + __expf(-gf)) * v;
          __builtin_nontemporal_store(f2bf(h), &G[(size_t)r * N + c]);
        } else {
          __builtin_nontemporal_store(v * Wt[r], &O[(size_t)r * N + c]);
        }
      }
    }
}

extern "C" void kernel_launch(void* const* d_in, const int* in_sizes, int n_in,
                              void* d_out, int out_size, void* d_ws, size_t ws_size,
                              hipStream_t stream) {
  const float* x   = (const float*)d_in[0];
  const float* Wg  = (const float*)d_in[1];
  const float* Wu  = (const float*)d_in[2];
  const float* Wd  = (const float*)d_in[3];
  const int*   top = (const int*)d_in[4];
  const float* wt  = (const float*)d_in[5];
  float* out = (float*)d_out;

  const size_t NE_X = (size_t)NSEL * HIDDEN;
  const size_t NE_W = (size_t)INTER * HIDDEN;
  if (ws_size < (NE_X + 3 * NE_W) * sizeof(uint16_t)) return;

  uint16_t* xs = (uint16_t*)d_ws;
  uint16_t* w1 = xs + NE_X;
  uint16_t* w2 = w1 + NE_W;
  uint16_t* gh = w2 + NE_W;

  const int WBLK = (int)(NE_W / (256 * 8));
  const int nbm  = NSEL / 256;      // 16
  const int nbn1 = INTER / 128;     // 112
  const int nbn2 = HIDDEN / 128;    // 32

  cvt_f32_bf16<<<WBLK, 256, 0, stream>>>(Wg, w1);
  cvt_f32_bf16<<<WBLK, 256, 0, stream>>>(Wu, w2);
  gather_cast<<<NSEL, 256, 0, stream>>>(x, top, xs);

  // gate: g = x_sel * Wg^T -> gh (bf16)
  gemm_nt<0><<<nbm * nbn1, 512, 0, stream>>>(xs, w1, gh, nullptr, nullptr,
                                             INTER, HIDDEN, nbm);
  // Wd -> w1 (after gate GEMM consumed Wg; stream-ordered)
  cvt_f32_bf16<<<WBLK, 256, 0, stream>>>(Wd, w1);
  // up + SwiGLU: h = silu(g) * (x_sel * Wu^T) -> gh in place
  gemm_nt<1><<<nbm * nbn1, 512, 0, stream>>>(xs, w2, gh, nullptr, nullptr,
                                             INTER, HIDDEN, nbm);
  // down + routing weight: out = (h * Wd^T) * weight[:,None]
  gemm_nt<2><<<nbm * nbn2, 512, 0, stream>>>(gh, w1, nullptr, out, wt,
                                             HIDDEN, INTER, nbm);
}